// Round 2
// 129.263 us; speedup vs baseline: 1.0202x; 1.0202x over previous
//
#include <hip/hip_runtime.h>

typedef unsigned short u16;
typedef unsigned int u32;
using frag8 = __attribute__((ext_vector_type(8))) short;  // 8 bf16 (4 VGPRs)
using f32x4 = __attribute__((ext_vector_type(4))) float;

#define MFMA(a, b, c) __builtin_amdgcn_mfma_f32_16x16x32_bf16(a, b, c, 0, 0, 0)

// fp32 -> bf16, round-to-nearest-even (finite inputs only)
__device__ __forceinline__ u16 f2bf(float f) {
  u32 x = __float_as_uint(f);
  x += 0x7fffu + ((x >> 16) & 1u);
  return (u16)(x >> 16);
}

// ---------------------------------------------------------------------------
// Pre-pass: qkv (4,1536,2048) fp32 ->
//   Qt[b][t][c] bf16 (scaled), Kt[b][s][c] bf16 (scaled), Vn[b][c][s] bf16
// Q,K pre-scaled by 64^-0.25 * sqrt(log2 e) so the flash kernel uses raw
// v_exp_f32.
// ---------------------------------------------------------------------------
__global__ __launch_bounds__(256) void qkv_prepass_kernel(
    const float* __restrict__ qkv, u16* __restrict__ Qt, u16* __restrict__ Kt,
    u16* __restrict__ Vn) {
  __shared__ float tile[64 * 65];
  const int id = blockIdx.x;
  const int tid = threadIdx.x;

  if (id < 2048) {
    const bool isK = id >= 1024;
    const int lid = isK ? (id - 1024) : id;
    const int b = lid >> 5;
    const int t0 = (lid & 31) * 64;
    const int bs = b >> 3, h = b & 7;
    const float* src =
        qkv + ((size_t)(bs * 1536 + h * 192 + (isK ? 64 : 0))) * 2048 + t0;
    u16* dst = (isK ? Kt : Qt) + ((size_t)b * 2048 + t0) * 64;
    const float scale = 0.42466090014400953f;  // 64^-0.25 * sqrt(log2 e)

    const int t4 = (tid & 15) * 4;
    const int c = tid >> 4;
#pragma unroll
    for (int i = 0; i < 4; ++i) {
      int cc = c + 16 * i;
      float4 f = *reinterpret_cast<const float4*>(src + (size_t)cc * 2048 + t4);
      tile[cc * 65 + t4 + 0] = f.x * scale;
      tile[cc * 65 + t4 + 1] = f.y * scale;
      tile[cc * 65 + t4 + 2] = f.z * scale;
      tile[cc * 65 + t4 + 3] = f.w * scale;
    }
    __syncthreads();
    const int c0 = (tid & 7) * 8;
#pragma unroll
    for (int p = 0; p < 2; ++p) {
      int tr = (tid >> 3) + 32 * p;
      u32 pk[4];
#pragma unroll
      for (int uu = 0; uu < 4; ++uu) {
        u16 lo = f2bf(tile[(c0 + 2 * uu) * 65 + tr]);
        u16 hi = f2bf(tile[(c0 + 2 * uu + 1) * 65 + tr]);
        pk[uu] = (u32)lo | ((u32)hi << 16);
      }
      *reinterpret_cast<uint4*>(dst + (size_t)tr * 64 + c0) =
          make_uint4(pk[0], pk[1], pk[2], pk[3]);
    }
  } else {
    const size_t base = (size_t)(id - 2048) * 4096;
#pragma unroll
    for (int it = 0; it < 2; ++it) {
      size_t vi = base + (size_t)it * 2048 + (size_t)tid * 8;
      int b = (int)(vi >> 17);
      int r = (int)(vi & 131071);
      int bs = b >> 3, h = b & 7;
      const float* sp = qkv + ((size_t)(bs * 1536 + h * 192 + 128)) * 2048 + r;
      float4 f0 = *reinterpret_cast<const float4*>(sp);
      float4 f1 = *reinterpret_cast<const float4*>(sp + 4);
      uint4 pk;
      pk.x = (u32)f2bf(f0.x) | ((u32)f2bf(f0.y) << 16);
      pk.y = (u32)f2bf(f0.z) | ((u32)f2bf(f0.w) << 16);
      pk.z = (u32)f2bf(f1.x) | ((u32)f2bf(f1.y) << 16);
      pk.w = (u32)f2bf(f1.z) | ((u32)f2bf(f1.w) << 16);
      *reinterpret_cast<uint4*>(Vn + vi) = pk;
    }
  }
}

// ---------------------------------------------------------------------------
// Flash attention, S^T form, no-max softmax, S-SPLIT:
// block = 4 waves = 2 t-groups (64 t) x 2 s-halves (16 tiles each).
// Grid 512 (XCD-swizzled) -> 2 blocks/CU = 8 waves/CU AND W=64 t/wave.
// R2: keep R1's VALU diet EXCEPT the cvt_pk pack (reverted to known-good
// perm-based pack — R1's absmax 0.19 matches a cvt_pk pair-swap/partial-write
// failure mode; the ones-MFMA l-sum is permutation/layout-invariant and
// provably consistent with the verified PV path, so it stays):
//  - row-sum l via ones-A MFMA on the same bf16 P the PV consumes
//    (removes 48 f32 adds/step/wave + the end shfl reduction)
//  - s_setprio(1) around MFMA clusters (2 unsynced blocks/CU -> T5 applies)
//  - epilogue O-exchange restrided to 68 floats (was 64 -> 16-acc/bank hotspot)
// LDS (u16 units, 64 KiB total):
//   [0,4096)      Q tg0 -> P of wave (tg0,sh0)
//   [4096,8192)   Q tg1 -> P of wave (tg1,sh0)
//   [8192,12288)  P of (tg0,sh1)      [12288,16384) P of (tg1,sh1)
//   [16384,20480) K stream sh0        [20480,24576) K stream sh1
//   [24576,28672) V stream sh0        [28672,32768) V stream sh1
// ---------------------------------------------------------------------------
#define STAGE(dstOff, srcPtr)                                                  \
  __builtin_amdgcn_global_load_lds(                                            \
      (const __attribute__((address_space(1))) void*)(srcPtr),                 \
      (__attribute__((address_space(3))) void*)(ldsbase + (dstOff) + tid * 8), \
      16, 0, 0)

// stage K tiles N (stream0) and N+16 (stream1), V likewise
#define STG_STEP(N)                                                         \
  STAGE(16384, Kg + (size_t)(N) * 4096 + koff0);                            \
  STAGE(16384 + 2048, Kg + (size_t)(N) * 4096 + koff0 + 2048);              \
  STAGE(20480, Kg + (size_t)((N) + 16) * 4096 + koff0);                     \
  STAGE(20480 + 2048, Kg + (size_t)((N) + 16) * 4096 + koff0 + 2048);       \
  STAGE(24576, Vg + (size_t)(N) * 64 + voff0);                              \
  STAGE(24576 + 2048, Vg + (size_t)(N) * 64 + voff0 + 65536);               \
  STAGE(28672, Vg + (size_t)((N) + 16) * 64 + voff0);                       \
  STAGE(28672 + 2048, Vg + (size_t)((N) + 16) * 64 + voff0 + 65536);

// step: read K/V frags of current tile -> barrier -> stage next (async) ->
// S MFMA -> exp/P-write -> P-read -> PV MFMA (+ones-MFMA l) -> barrier
#define BODY(STG)                                                           \
  {                                                                         \
    frag8 kf0[4], kf1[4], vf0[4], vf1[4];                                   \
    _Pragma("unroll") for (int i = 0; i < 4; ++i) {                         \
      kf0[i] = *(const frag8*)(kBa + i * 1024);                             \
      kf1[i] = *(const frag8*)(kBb + i * 1024);                             \
      vf0[i] = *(const frag8*)(vBa + i * 1024);                             \
      vf1[i] = *(const frag8*)(vBb + i * 1024);                             \
    }                                                                       \
    __syncthreads(); /* all waves done reading the single buffers */        \
    STG                                                                     \
    f32x4 S[4][4];                                                          \
    __builtin_amdgcn_s_setprio(1);                                          \
    _Pragma("unroll") for (int i = 0; i < 4; ++i) {                         \
      _Pragma("unroll") for (int j = 0; j < 4; ++j) {                       \
        f32x4 z = {0.f, 0.f, 0.f, 0.f};                                     \
        z = MFMA(kf0[i], aQ0[j], z);                                        \
        z = MFMA(kf1[i], aQ1[j], z);                                        \
        S[i][j] = z;                                                        \
      }                                                                     \
    }                                                                       \
    __builtin_amdgcn_s_setprio(0);                                          \
    _Pragma("unroll") for (int j = 0; j < 4; ++j) {                         \
      _Pragma("unroll") for (int i = 0; i < 4; ++i) {                       \
        float p0 = __builtin_amdgcn_exp2f(S[i][j][0]);                      \
        float p1 = __builtin_amdgcn_exp2f(S[i][j][1]);                      \
        float p2 = __builtin_amdgcn_exp2f(S[i][j][2]);                      \
        float p3 = __builtin_amdgcn_exp2f(S[i][j][3]);                      \
        u32 a0 = __float_as_uint(p0) + 0x8000u;                             \
        u32 a1 = __float_as_uint(p1) + 0x8000u;                             \
        u32 a2 = __float_as_uint(p2) + 0x8000u;                             \
        u32 a3 = __float_as_uint(p3) + 0x8000u;                             \
        *(uint2*)(pPb + j * 1024 + pslot[i]) =                              \
            make_uint2(__builtin_amdgcn_perm(a1, a0, 0x07060302u),          \
                       __builtin_amdgcn_perm(a3, a2, 0x07060302u));         \
      }                                                                     \
    }                                                                       \
    asm volatile("" ::: "memory"); /* P-writes ordered before P-reads */    \
    {                                                                       \
      frag8 pf0[4], pf1[4];                                                 \
      _Pragma("unroll") for (int j = 0; j < 4; ++j) {                       \
        pf0[j] = *(const frag8*)(pPb + j * 1024 + off0);                    \
        pf1[j] = *(const frag8*)(pPb + j * 1024 + off1);                    \
      }                                                                     \
      __builtin_amdgcn_s_setprio(1);                                        \
      _Pragma("unroll") for (int i = 0; i < 4; ++i) {                       \
        _Pragma("unroll") for (int j = 0; j < 4; ++j) {                     \
          o[i][j] = MFMA(vf0[i], pf0[j], o[i][j]);                          \
          o[i][j] = MFMA(vf1[i], pf1[j], o[i][j]);                          \
        }                                                                   \
      }                                                                     \
      _Pragma("unroll") for (int j = 0; j < 4; ++j) {                       \
        lacc[j] = MFMA(ones, pf0[j], lacc[j]);                              \
        lacc[j] = MFMA(ones, pf1[j], lacc[j]);                              \
      }                                                                     \
      __builtin_amdgcn_s_setprio(0);                                        \
    }                                                                       \
    __syncthreads(); /* staging complete (vmcnt drained) */                 \
  }

__global__ __launch_bounds__(256, 2) void attn_flash_kernel(
    const u16* __restrict__ Qt, const u16* __restrict__ Kt,
    const u16* __restrict__ Vn, float* __restrict__ out) {
  __shared__ __align__(16) unsigned char smem[65536];
  u16* ldsbase = (u16*)smem;

  // XCD swizzle: blk&7 = XCD; 4 heads per XCD (K+V L2-resident per XCD)
  const int blk = blockIdx.x;
  const int ii = blk >> 3;
  const int b = ((blk & 7) << 2) + (ii >> 4);  // head 0..31
  const int qt = ii & 15;                      // q-tile (128 t each)

  const int tid = threadIdx.x;
  const int w = tid >> 6;
  const int tg = w & 1;   // t-group: t in [64*tg, 64*tg+64) of the q-tile
  const int sh = w >> 1;  // s-half: tiles [16*sh, 16*sh+16)
  const int lane = tid & 63;
  const int s16 = lane & 15, q = lane >> 4;
  const int x = s16 & 7;

  const u16* Qg = Qt + ((size_t)b * 2048 + qt * 128) * 64;
  const u16* Kg = Kt + (size_t)b * 2048 * 64;
  const u16* Vg = Vn + (size_t)b * 64 * 2048;

  // staging lane offsets (u16 units)
  const int srow = tid >> 3;
  const int sgl = (tid & 7) ^ (srow & 7);
  const int koff0 = srow * 64 + sgl * 8;    // pitch-64 tiles (Q,K)
  const int voff0 = srow * 2048 + sgl * 8;  // pitch-2048 (V)

  // fragment read bases for this wave's s-stream (XOR-swizzled)
  const u16* kBa = ldsbase + 16384 + sh * 4096 + s16 * 64 + ((q ^ x) * 8);
  const u16* kBb = ldsbase + 16384 + sh * 4096 + s16 * 64 + (((q + 4) ^ x) * 8);
  const u16* vBa = ldsbase + 24576 + sh * 4096 + s16 * 64 + ((q ^ x) * 8);
  const u16* vBb = ldsbase + 24576 + sh * 4096 + s16 * 64 + (((q + 4) ^ x) * 8);
  // Q rows of this t-group; P region private to this (tg,sh) wave
  const u16* pqb = ldsbase + tg * 4096 + s16 * 64;
  u16* pPb = ldsbase + tg * 4096 + sh * 8192 + s16 * 64;
  const int off0 = (q ^ x) * 8;
  const int off1 = ((q + 4) ^ x) * 8;
  int pslot[4];
#pragma unroll
  for (int i = 0; i < 4; ++i)
    pslot[i] = ((2 * i + (q >> 1)) ^ x) * 8 + (q & 1) * 4;

  // prologue: stage Q (128x64, 4 calls) + K/V tiles {0,16}
  STAGE(0, Qg + koff0);
  STAGE(2048, Qg + koff0 + 2048);
  STAGE(4096, Qg + koff0 + 4096);
  STAGE(6144, Qg + koff0 + 6144);
  STG_STEP(0)
  __syncthreads();

  // loop-invariant Q fragments (both s-half waves read the shared Q rows)
  frag8 aQ0[4], aQ1[4];
#pragma unroll
  for (int j = 0; j < 4; ++j) {
    aQ0[j] = *(const frag8*)(pqb + j * 1024 + off0);
    aQ1[j] = *(const frag8*)(pqb + j * 1024 + off1);
  }
  __syncthreads();  // Q consumed by all before sh=0 overwrites it with P

  // ones A-fragment (bf16 1.0) for the row-sum MFMA
  frag8 ones;
#pragma unroll
  for (int z = 0; z < 8; ++z) ones[z] = (short)0x3F80;

  f32x4 o[4][4];
#pragma unroll
  for (int i = 0; i < 4; ++i)
#pragma unroll
    for (int j = 0; j < 4; ++j) o[i][j] = (f32x4){0.f, 0.f, 0.f, 0.f};
  f32x4 lacc[4];
#pragma unroll
  for (int j = 0; j < 4; ++j) lacc[j] = (f32x4){0.f, 0.f, 0.f, 0.f};

  for (int n = 0; n < 15; ++n) {
    BODY(STG_STEP(n + 1))
  }
  BODY()  // tile 15 / 31, nothing left to stage

  // per-wave denominators: ones-MFMA summed all s of this wave's range for
  // t = 16j + s16 (every acc row identical) — no cross-lane reduction needed
  float lp[4];
#pragma unroll
  for (int j = 0; j < 4; ++j) lp[j] = lacc[j][0];

  // combine s-halves through LDS (K/V + P regions are free now)
  // O rows restrided to 68 floats (272 B) -> 4-bank rotation per lane
  if (sh == 1) {
    float* ow = (float*)ldsbase + tg * 4352 + lane * 68;
#pragma unroll
    for (int i = 0; i < 4; ++i)
#pragma unroll
      for (int j = 0; j < 4; ++j) *(f32x4*)(ow + (i * 4 + j) * 4) = o[i][j];
    float* lw = (float*)ldsbase + 8704 + tg * 256 + lane * 4;
#pragma unroll
    for (int j = 0; j < 4; ++j) lw[j] = lp[j];
  }
  __syncthreads();
  if (sh == 0) {
    const float* ow = (const float*)ldsbase + tg * 4352 + lane * 68;
    const float* lw = (const float*)ldsbase + 8704 + tg * 256 + lane * 4;
    float rl[4];
#pragma unroll
    for (int j = 0; j < 4; ++j) rl[j] = 1.0f / (lp[j] + lw[j]);
    // lane stores O^T[c = i*16+q*4+r][t = qt*128 + tg*64 + 16j + s16]
    float* ob =
        out + (size_t)(b * 64 + q * 4) * 2048 + qt * 128 + tg * 64 + s16;
#pragma unroll
    for (int i = 0; i < 4; ++i)
#pragma unroll
      for (int j = 0; j < 4; ++j) {
        f32x4 oo = *(const f32x4*)(ow + (i * 4 + j) * 4);
#pragma unroll
        for (int r = 0; r < 4; ++r)
          ob[(size_t)(i * 16 + r) * 2048 + j * 16] =
              (o[i][j][r] + oo[r]) * rl[j];
      }
  }
}

extern "C" void kernel_launch(void* const* d_in, const int* in_sizes, int n_in,
                              void* d_out, int out_size, void* d_ws,
                              size_t ws_size, hipStream_t stream) {
  const float* qkv = (const float*)d_in[0];
  float* out = (float*)d_out;
  u16* Qt = (u16*)d_ws;
  u16* Kt = Qt + (size_t)32 * 2048 * 64;
  u16* Vn = Kt + (size_t)32 * 2048 * 64;

  qkv_prepass_kernel<<<3072, 256, 0, stream>>>(qkv, Qt, Kt, Vn);
  attn_flash_kernel<<<512, 256, 0, stream>>>(Qt, Kt, Vn, out);
}

// Round 3
// 124.006 us; speedup vs baseline: 1.0635x; 1.0424x over previous
//
#include <hip/hip_runtime.h>

typedef unsigned short u16;
typedef unsigned int u32;
using frag8 = __attribute__((ext_vector_type(8))) short;  // 8 bf16 (4 VGPRs)
using f32x4 = __attribute__((ext_vector_type(4))) float;
using u32x4 = __attribute__((ext_vector_type(4))) u32;

#define MFMA(a, b, c) __builtin_amdgcn_mfma_f32_16x16x32_bf16(a, b, c, 0, 0, 0)

// fp32 -> bf16, round-to-nearest-even (finite inputs only)
__device__ __forceinline__ u16 f2bf(float f) {
  u32 x = __float_as_uint(f);
  x += 0x7fffu + ((x >> 16) & 1u);
  return (u16)(x >> 16);
}

// ---------------------------------------------------------------------------
// Pre-pass: qkv (4,1536,2048) fp32 ->
//   Qt[b][t][c] bf16 (scaled), Kt[b][s][c] bf16 (scaled),
//   Vn[b][c][s'] bf16 with s sigma-PERMUTED within each 64-s tile:
//     stored position p (h=p>>5, w=(p>>3)&3, e=p&7) holds original
//     s = 32h + 16*(e>>2) + 4w + (e&3).
// This makes QK^T's D-fragment directly usable as PV's B-fragment (the
// k-permutation cancels between P and V), eliminating the P LDS round-trip
// in the flash kernel.
// ---------------------------------------------------------------------------
__global__ __launch_bounds__(256) void qkv_prepass_kernel(
    const float* __restrict__ qkv, u16* __restrict__ Qt, u16* __restrict__ Kt,
    u16* __restrict__ Vn) {
  __shared__ float tile[64 * 65];
  const int id = blockIdx.x;
  const int tid = threadIdx.x;

  if (id < 2048) {
    const bool isK = id >= 1024;
    const int lid = isK ? (id - 1024) : id;
    const int b = lid >> 5;
    const int t0 = (lid & 31) * 64;
    const int bs = b >> 3, h = b & 7;
    const float* src =
        qkv + ((size_t)(bs * 1536 + h * 192 + (isK ? 64 : 0))) * 2048 + t0;
    u16* dst = (isK ? Kt : Qt) + ((size_t)b * 2048 + t0) * 64;
    const float scale = 0.42466090014400953f;  // 64^-0.25 * sqrt(log2 e)

    const int t4 = (tid & 15) * 4;
    const int c = tid >> 4;
#pragma unroll
    for (int i = 0; i < 4; ++i) {
      int cc = c + 16 * i;
      float4 f = *reinterpret_cast<const float4*>(src + (size_t)cc * 2048 + t4);
      tile[cc * 65 + t4 + 0] = f.x * scale;
      tile[cc * 65 + t4 + 1] = f.y * scale;
      tile[cc * 65 + t4 + 2] = f.z * scale;
      tile[cc * 65 + t4 + 3] = f.w * scale;
    }
    __syncthreads();
    const int c0 = (tid & 7) * 8;
#pragma unroll
    for (int p = 0; p < 2; ++p) {
      int tr = (tid >> 3) + 32 * p;
      u32 pk[4];
#pragma unroll
      for (int uu = 0; uu < 4; ++uu) {
        u16 lo = f2bf(tile[(c0 + 2 * uu) * 65 + tr]);
        u16 hi = f2bf(tile[(c0 + 2 * uu + 1) * 65 + tr]);
        pk[uu] = (u32)lo | ((u32)hi << 16);
      }
      *reinterpret_cast<uint4*>(dst + (size_t)tr * 64 + c0) =
          make_uint4(pk[0], pk[1], pk[2], pk[3]);
    }
  } else {
    const size_t base = (size_t)(id - 2048) * 4096;
#pragma unroll
    for (int it = 0; it < 2; ++it) {
      size_t vi = base + (size_t)it * 2048 + (size_t)tid * 8;
      int b = (int)(vi >> 17);
      int r = (int)(vi & 131071);
      int bs = b >> 3, h = b & 7;
      int col = r & 2047;      // stored position within the c-row
      int rowoff = r - col;    // c * 2048
      int m = (col >> 3) & 7;  // 8-run index within the 64-s tile
      // source column of stored e=0..3 run: tilebase + 32h + 4w
      int c0 = (col & ~63) | ((m >> 2) << 5) | ((m & 3) << 2);
      const float* sp =
          qkv + ((size_t)(bs * 1536 + h * 192 + 128)) * 2048 + rowoff;
      float4 f0 = *reinterpret_cast<const float4*>(sp + c0);       // e=0..3
      float4 f1 = *reinterpret_cast<const float4*>(sp + c0 + 16);  // e=4..7
      uint4 pk;
      pk.x = (u32)f2bf(f0.x) | ((u32)f2bf(f0.y) << 16);
      pk.y = (u32)f2bf(f0.z) | ((u32)f2bf(f0.w) << 16);
      pk.z = (u32)f2bf(f1.x) | ((u32)f2bf(f1.y) << 16);
      pk.w = (u32)f2bf(f1.z) | ((u32)f2bf(f1.w) << 16);
      *reinterpret_cast<uint4*>(Vn + vi) = pk;
    }
  }
}

// ---------------------------------------------------------------------------
// Flash attention, S^T form, no-max softmax, S-SPLIT, in-register P (R3):
// block = 4 waves = 2 t-groups (64 t) x 2 s-halves (16 tiles each).
// Grid 512 (XCD-swizzled) -> 2 blocks/CU = 8 waves/CU.
// R3 changes:
//  - P never touches LDS: sigma-permuted V (prepass) makes QK^T's D-layout a
//    valid PV B-layout -> pf = in-register pack of S. Removes 16 ds_write_b64
//    + 8 ds_read_b128 per wave-step (-40% LDS traffic).
//  - freed 16 KiB -> K/V double-buffered: stage into buf^1 while computing
//    buf -> ONE barrier per step (was 2).
// LDS (u16 units, 64 KiB total):
//   buf0 [0,16384):     K sh0 [0,4K) K sh1 [4K,8K) V sh0 [8K,12K) V sh1 [12K,16K)
//   buf1 [16384,32768): same layout; Q (prologue only) overlaps buf1[0,8192)
//   epilogue O/l exchange reuses [0, ~36 KiB) after the final barrier
// ---------------------------------------------------------------------------
#define STAGE(dstOff, srcPtr)                                                  \
  __builtin_amdgcn_global_load_lds(                                            \
      (const __attribute__((address_space(1))) void*)(srcPtr),                 \
      (__attribute__((address_space(3))) void*)(ldsbase + (dstOff) + tid * 8), \
      16, 0, 0)

// stage K tiles N (stream sh0) and N+16 (stream sh1), V likewise, into buf B
#define STG_STEP(N, B)                                                      \
  STAGE((B), Kg + (size_t)(N) * 4096 + koff0);                              \
  STAGE((B) + 2048, Kg + (size_t)(N) * 4096 + koff0 + 2048);                \
  STAGE((B) + 4096, Kg + (size_t)((N) + 16) * 4096 + koff0);                \
  STAGE((B) + 6144, Kg + (size_t)((N) + 16) * 4096 + koff0 + 2048);         \
  STAGE((B) + 8192, Vg + (size_t)(N) * 64 + voff0);                         \
  STAGE((B) + 10240, Vg + (size_t)(N) * 64 + voff0 + 65536);                \
  STAGE((B) + 12288, Vg + (size_t)((N) + 16) * 64 + voff0);                 \
  STAGE((B) + 14336, Vg + (size_t)((N) + 16) * 64 + voff0 + 65536);

// step: read K/V frags from buf CUR -> stage next tiles into buf CUR^1
// (async, no hazard: different buffer) -> S MFMA -> exp/pack (in-register)
// -> PV MFMA (+ones-MFMA l) -> barrier (staging drained, next buf ready)
#define BODY(CUR, STG)                                                      \
  {                                                                         \
    frag8 kf0[4], kf1[4], vf0[4], vf1[4];                                   \
    _Pragma("unroll") for (int i = 0; i < 4; ++i) {                         \
      kf0[i] = *(const frag8*)(ldsbase + (CUR) + kAo + i * 1024);           \
      kf1[i] = *(const frag8*)(ldsbase + (CUR) + kBo + i * 1024);           \
      vf0[i] = *(const frag8*)(ldsbase + (CUR) + vAo + i * 1024);           \
      vf1[i] = *(const frag8*)(ldsbase + (CUR) + vBo + i * 1024);           \
    }                                                                       \
    STG                                                                     \
    f32x4 S[4][4];                                                          \
    __builtin_amdgcn_s_setprio(1);                                          \
    _Pragma("unroll") for (int i = 0; i < 4; ++i) {                         \
      _Pragma("unroll") for (int j = 0; j < 4; ++j) {                       \
        f32x4 z = {0.f, 0.f, 0.f, 0.f};                                     \
        z = MFMA(kf0[i], aQ0[j], z);                                        \
        z = MFMA(kf1[i], aQ1[j], z);                                        \
        S[i][j] = z;                                                        \
      }                                                                     \
    }                                                                       \
    __builtin_amdgcn_s_setprio(0);                                          \
    frag8 pf0[4], pf1[4];                                                   \
    _Pragma("unroll") for (int j = 0; j < 4; ++j) {                         \
      u32 pw[8];                                                            \
      _Pragma("unroll") for (int i = 0; i < 4; ++i) {                       \
        float p0 = __builtin_amdgcn_exp2f(S[i][j][0]);                      \
        float p1 = __builtin_amdgcn_exp2f(S[i][j][1]);                      \
        float p2 = __builtin_amdgcn_exp2f(S[i][j][2]);                      \
        float p3 = __builtin_amdgcn_exp2f(S[i][j][3]);                      \
        u32 a0 = __float_as_uint(p0) + 0x8000u;                             \
        u32 a1 = __float_as_uint(p1) + 0x8000u;                             \
        u32 a2 = __float_as_uint(p2) + 0x8000u;                             \
        u32 a3 = __float_as_uint(p3) + 0x8000u;                             \
        pw[i * 2] = __builtin_amdgcn_perm(a1, a0, 0x07060302u);             \
        pw[i * 2 + 1] = __builtin_amdgcn_perm(a3, a2, 0x07060302u);         \
      }                                                                     \
      u32x4 va = {pw[0], pw[1], pw[2], pw[3]};                              \
      u32x4 vb = {pw[4], pw[5], pw[6], pw[7]};                              \
      pf0[j] = __builtin_bit_cast(frag8, va);                               \
      pf1[j] = __builtin_bit_cast(frag8, vb);                               \
    }                                                                       \
    __builtin_amdgcn_s_setprio(1);                                          \
    _Pragma("unroll") for (int i = 0; i < 4; ++i) {                         \
      _Pragma("unroll") for (int j = 0; j < 4; ++j) {                       \
        o[i][j] = MFMA(vf0[i], pf0[j], o[i][j]);                            \
        o[i][j] = MFMA(vf1[i], pf1[j], o[i][j]);                            \
      }                                                                     \
    }                                                                       \
    _Pragma("unroll") for (int j = 0; j < 4; ++j) {                         \
      lacc[j] = MFMA(ones, pf0[j], lacc[j]);                                \
      lacc[j] = MFMA(ones, pf1[j], lacc[j]);                                \
    }                                                                       \
    __builtin_amdgcn_s_setprio(0);                                          \
    __syncthreads(); /* staging drained; buf CUR^1 ready */                 \
  }

__global__ __launch_bounds__(256, 2) void attn_flash_kernel(
    const u16* __restrict__ Qt, const u16* __restrict__ Kt,
    const u16* __restrict__ Vn, float* __restrict__ out) {
  __shared__ __align__(16) unsigned char smem[65536];
  u16* ldsbase = (u16*)smem;

  // XCD swizzle: blk&7 = XCD; 4 heads per XCD (K+V L2-resident per XCD)
  const int blk = blockIdx.x;
  const int ii = blk >> 3;
  const int b = ((blk & 7) << 2) + (ii >> 4);  // head 0..31
  const int qt = ii & 15;                      // q-tile (128 t each)

  const int tid = threadIdx.x;
  const int w = tid >> 6;
  const int tg = w & 1;   // t-group: t in [64*tg, 64*tg+64) of the q-tile
  const int sh = w >> 1;  // s-half: tiles [16*sh, 16*sh+16)
  const int lane = tid & 63;
  const int s16 = lane & 15, q = lane >> 4;
  const int x = s16 & 7;

  const u16* Qg = Qt + ((size_t)b * 2048 + qt * 128) * 64;
  const u16* Kg = Kt + (size_t)b * 2048 * 64;
  const u16* Vg = Vn + (size_t)b * 64 * 2048;

  // staging lane offsets (u16 units)
  const int srow = tid >> 3;
  const int sgl = (tid & 7) ^ (srow & 7);
  const int koff0 = srow * 64 + sgl * 8;    // pitch-64 tiles (Q,K)
  const int voff0 = srow * 2048 + sgl * 8;  // pitch-2048 (V)

  // fragment read offsets within a buffer (XOR-swizzled)
  const int kAo = sh * 4096 + s16 * 64 + ((q ^ x) * 8);
  const int kBo = sh * 4096 + s16 * 64 + (((q + 4) ^ x) * 8);
  const int vAo = 8192 + sh * 4096 + s16 * 64 + ((q ^ x) * 8);
  const int vBo = 8192 + sh * 4096 + s16 * 64 + (((q + 4) ^ x) * 8);
  const int off0 = (q ^ x) * 8;
  const int off1 = ((q + 4) ^ x) * 8;

  // prologue: stage Q (128x64 -> buf1 area) + K/V tiles {0,16} -> buf0
  STAGE(16384, Qg + koff0);
  STAGE(16384 + 2048, Qg + koff0 + 2048);
  STAGE(16384 + 4096, Qg + koff0 + 4096);
  STAGE(16384 + 6144, Qg + koff0 + 6144);
  STG_STEP(0, 0)
  __syncthreads();

  // loop-invariant Q fragments (both s-half waves read the shared Q rows)
  const u16* pqb = ldsbase + 16384 + tg * 4096 + s16 * 64;
  frag8 aQ0[4], aQ1[4];
#pragma unroll
  for (int j = 0; j < 4; ++j) {
    aQ0[j] = *(const frag8*)(pqb + j * 1024 + off0);
    aQ1[j] = *(const frag8*)(pqb + j * 1024 + off1);
  }
  __syncthreads();  // Q consumed by all before step 0 stages tile 1 over it

  // ones A-fragment (bf16 1.0) for the row-sum MFMA
  frag8 ones;
#pragma unroll
  for (int z = 0; z < 8; ++z) ones[z] = (short)0x3F80;

  f32x4 o[4][4];
#pragma unroll
  for (int i = 0; i < 4; ++i)
#pragma unroll
    for (int j = 0; j < 4; ++j) o[i][j] = (f32x4){0.f, 0.f, 0.f, 0.f};
  f32x4 lacc[4];
#pragma unroll
  for (int j = 0; j < 4; ++j) lacc[j] = (f32x4){0.f, 0.f, 0.f, 0.f};

  for (int n = 0; n < 14; n += 2) {
    BODY(0, STG_STEP(n + 1, 16384))
    BODY(16384, STG_STEP(n + 2, 0))
  }
  BODY(0, STG_STEP(15, 16384))
  BODY(16384, )  // tile 15/31, nothing left to stage

  // per-wave denominators: ones-MFMA summed all s of this wave's range for
  // t = 16j + s16 (every acc row identical) — no cross-lane reduction needed
  float lp[4];
#pragma unroll
  for (int j = 0; j < 4; ++j) lp[j] = lacc[j][0];

  // combine s-halves through LDS (all K/V buffers dead after final barrier)
  // O rows strided 68 floats (272 B) -> 4-bank rotation per lane
  if (sh == 1) {
    float* ow = (float*)ldsbase + tg * 4352 + lane * 68;
#pragma unroll
    for (int i = 0; i < 4; ++i)
#pragma unroll
      for (int j = 0; j < 4; ++j) *(f32x4*)(ow + (i * 4 + j) * 4) = o[i][j];
    float* lw = (float*)ldsbase + 8704 + tg * 256 + lane * 4;
#pragma unroll
    for (int j = 0; j < 4; ++j) lw[j] = lp[j];
  }
  __syncthreads();
  if (sh == 0) {
    const float* ow = (const float*)ldsbase + tg * 4352 + lane * 68;
    const float* lw = (const float*)ldsbase + 8704 + tg * 256 + lane * 4;
    float rl[4];
#pragma unroll
    for (int j = 0; j < 4; ++j) rl[j] = 1.0f / (lp[j] + lw[j]);
    // lane stores O^T[c = i*16+q*4+r][t = qt*128 + tg*64 + 16j + s16]
    float* ob =
        out + (size_t)(b * 64 + q * 4) * 2048 + qt * 128 + tg * 64 + s16;
#pragma unroll
    for (int i = 0; i < 4; ++i)
#pragma unroll
      for (int j = 0; j < 4; ++j) {
        f32x4 oo = *(const f32x4*)(ow + (i * 4 + j) * 4);
#pragma unroll
        for (int r = 0; r < 4; ++r)
          ob[(size_t)(i * 16 + r) * 2048 + j * 16] =
              (o[i][j][r] + oo[r]) * rl[j];
      }
  }
}

extern "C" void kernel_launch(void* const* d_in, const int* in_sizes, int n_in,
                              void* d_out, int out_size, void* d_ws,
                              size_t ws_size, hipStream_t stream) {
  const float* qkv = (const float*)d_in[0];
  float* out = (float*)d_out;
  u16* Qt = (u16*)d_ws;
  u16* Kt = Qt + (size_t)32 * 2048 * 64;
  u16* Vn = Kt + (size_t)32 * 2048 * 64;

  qkv_prepass_kernel<<<3072, 256, 0, stream>>>(qkv, Qt, Kt, Vn);
  attn_flash_kernel<<<512, 256, 0, stream>>>(Qt, Kt, Vn, out);
}

// Round 5
// 123.839 us; speedup vs baseline: 1.0649x; 1.0013x over previous
//
#include <hip/hip_runtime.h>

typedef unsigned short u16;
typedef unsigned int u32;
using frag8 = __attribute__((ext_vector_type(8))) short;  // 8 bf16 (4 VGPRs)
using f32x4 = __attribute__((ext_vector_type(4))) float;
using u32x4 = __attribute__((ext_vector_type(4))) u32;

#define MFMA(a, b, c) __builtin_amdgcn_mfma_f32_16x16x32_bf16(a, b, c, 0, 0, 0)

// fp32 -> bf16, round-to-nearest-even (finite inputs only)
__device__ __forceinline__ u16 f2bf(float f) {
  u32 x = __float_as_uint(f);
  x += 0x7fffu + ((x >> 16) & 1u);
  return (u16)(x >> 16);
}

// ---------------------------------------------------------------------------
// Pre-pass: qkv (4,1536,2048) fp32 ->
//   Qt[b][t][c] bf16 (scaled), Kt[b][s][c] bf16 (scaled),
//   Vn[b][c][s'] bf16 with s sigma-PERMUTED within each 64-s tile:
//     stored position p (h=p>>5, w=(p>>3)&3, e=p&7) holds original
//     s = 32h + 16*(e>>2) + 4w + (e&3).
// This makes QK^T's D-fragment directly usable as PV's B-fragment (the
// k-permutation cancels between P and V), eliminating the P LDS round-trip
// in the flash kernel.
// ---------------------------------------------------------------------------
__global__ __launch_bounds__(256) void qkv_prepass_kernel(
    const float* __restrict__ qkv, u16* __restrict__ Qt, u16* __restrict__ Kt,
    u16* __restrict__ Vn) {
  __shared__ float tile[64 * 65];
  const int id = blockIdx.x;
  const int tid = threadIdx.x;

  if (id < 2048) {
    const bool isK = id >= 1024;
    const int lid = isK ? (id - 1024) : id;
    const int b = lid >> 5;
    const int t0 = (lid & 31) * 64;
    const int bs = b >> 3, h = b & 7;
    const float* src =
        qkv + ((size_t)(bs * 1536 + h * 192 + (isK ? 64 : 0))) * 2048 + t0;
    u16* dst = (isK ? Kt : Qt) + ((size_t)b * 2048 + t0) * 64;
    const float scale = 0.42466090014400953f;  // 64^-0.25 * sqrt(log2 e)

    const int t4 = (tid & 15) * 4;
    const int c = tid >> 4;
#pragma unroll
    for (int i = 0; i < 4; ++i) {
      int cc = c + 16 * i;
      float4 f = *reinterpret_cast<const float4*>(src + (size_t)cc * 2048 + t4);
      tile[cc * 65 + t4 + 0] = f.x * scale;
      tile[cc * 65 + t4 + 1] = f.y * scale;
      tile[cc * 65 + t4 + 2] = f.z * scale;
      tile[cc * 65 + t4 + 3] = f.w * scale;
    }
    __syncthreads();
    const int c0 = (tid & 7) * 8;
#pragma unroll
    for (int p = 0; p < 2; ++p) {
      int tr = (tid >> 3) + 32 * p;
      u32 pk[4];
#pragma unroll
      for (int uu = 0; uu < 4; ++uu) {
        u16 lo = f2bf(tile[(c0 + 2 * uu) * 65 + tr]);
        u16 hi = f2bf(tile[(c0 + 2 * uu + 1) * 65 + tr]);
        pk[uu] = (u32)lo | ((u32)hi << 16);
      }
      *reinterpret_cast<uint4*>(dst + (size_t)tr * 64 + c0) =
          make_uint4(pk[0], pk[1], pk[2], pk[3]);
    }
  } else {
    const size_t base = (size_t)(id - 2048) * 4096;
#pragma unroll
    for (int it = 0; it < 2; ++it) {
      size_t vi = base + (size_t)it * 2048 + (size_t)tid * 8;
      int b = (int)(vi >> 17);
      int r = (int)(vi & 131071);
      int bs = b >> 3, h = b & 7;
      int col = r & 2047;      // stored position within the c-row
      int rowoff = r - col;    // c * 2048
      int m = (col >> 3) & 7;  // 8-run index within the 64-s tile
      // source column of stored e=0..3 run: tilebase + 32h + 4w
      int c0 = (col & ~63) | ((m >> 2) << 5) | ((m & 3) << 2);
      const float* sp =
          qkv + ((size_t)(bs * 1536 + h * 192 + 128)) * 2048 + rowoff;
      float4 f0 = *reinterpret_cast<const float4*>(sp + c0);       // e=0..3
      float4 f1 = *reinterpret_cast<const float4*>(sp + c0 + 16);  // e=4..7
      uint4 pk;
      pk.x = (u32)f2bf(f0.x) | ((u32)f2bf(f0.y) << 16);
      pk.y = (u32)f2bf(f0.z) | ((u32)f2bf(f0.w) << 16);
      pk.z = (u32)f2bf(f1.x) | ((u32)f2bf(f1.y) << 16);
      pk.w = (u32)f2bf(f1.z) | ((u32)f2bf(f1.w) << 16);
      *reinterpret_cast<uint4*>(Vn + vi) = pk;
    }
  }
}

// ---------------------------------------------------------------------------
// Flash attention, S^T form, no-max softmax, S-SPLIT, in-register P.
// block = 4 waves = 2 t-groups (64 t) x 2 s-halves (16 tiles each).
// Grid 512 (XCD-swizzled) -> 2 blocks/CU = 8 waves/CU.
// R5 = R3 + braided j-loop only (R4's __floats2bfloat162_rn doesn't exist in
// this ROCm; pack stays the VERIFIED +0x8000/v_perm form):
//  - braided j-loop: S j-outer, then per-j {exp/pack -> PV + lacc}. The
//    ~220-instr VALU softmax wall becomes 4 x ~55-instr chunks with 10-MFMA
//    bursts between -> matrix pipe stays fed during softmax (in-order issue,
//    non-blocking pipes: pack(j+1) issues while PV(j) drains).
//  - vf ds_reads deferred to after the S phase (current buffer is stable all
//    step; only the staging buffer flips) -> lower S-phase VGPR pressure.
// LDS (u16 units, 64 KiB total):
//   buf0 [0,16384):     K sh0 [0,4K) K sh1 [4K,8K) V sh0 [8K,12K) V sh1 [12K,16K)
//   buf1 [16384,32768): same layout; Q (prologue only) overlaps buf1[0,8192)
//   epilogue O/l exchange reuses [0, ~36 KiB) after the final barrier
// ---------------------------------------------------------------------------
#define STAGE(dstOff, srcPtr)                                                  \
  __builtin_amdgcn_global_load_lds(                                            \
      (const __attribute__((address_space(1))) void*)(srcPtr),                 \
      (__attribute__((address_space(3))) void*)(ldsbase + (dstOff) + tid * 8), \
      16, 0, 0)

// stage K tiles N (stream sh0) and N+16 (stream sh1), V likewise, into buf B
#define STG_STEP(N, B)                                                      \
  STAGE((B), Kg + (size_t)(N) * 4096 + koff0);                              \
  STAGE((B) + 2048, Kg + (size_t)(N) * 4096 + koff0 + 2048);                \
  STAGE((B) + 4096, Kg + (size_t)((N) + 16) * 4096 + koff0);                \
  STAGE((B) + 6144, Kg + (size_t)((N) + 16) * 4096 + koff0 + 2048);         \
  STAGE((B) + 8192, Vg + (size_t)(N) * 64 + voff0);                         \
  STAGE((B) + 10240, Vg + (size_t)(N) * 64 + voff0 + 65536);                \
  STAGE((B) + 12288, Vg + (size_t)((N) + 16) * 64 + voff0);                 \
  STAGE((B) + 14336, Vg + (size_t)((N) + 16) * 64 + voff0 + 65536);

// step: read K frags from buf CUR -> stage next tiles into buf CUR^1 (async,
// no hazard: different buffer) -> S MFMA (j-outer) -> vf reads -> braided
// per-j {exp/pack -> PV MFMA + ones-MFMA l} -> barrier (staging drained)
#define BODY(CUR, STG)                                                      \
  {                                                                         \
    frag8 kf0[4], kf1[4];                                                   \
    _Pragma("unroll") for (int i = 0; i < 4; ++i) {                         \
      kf0[i] = *(const frag8*)(ldsbase + (CUR) + kAo + i * 1024);           \
      kf1[i] = *(const frag8*)(ldsbase + (CUR) + kBo + i * 1024);           \
    }                                                                       \
    STG                                                                     \
    f32x4 S[4][4];                                                          \
    __builtin_amdgcn_s_setprio(1);                                          \
    _Pragma("unroll") for (int j = 0; j < 4; ++j) {                         \
      _Pragma("unroll") for (int i = 0; i < 4; ++i) {                       \
        f32x4 z = {0.f, 0.f, 0.f, 0.f};                                     \
        z = MFMA(kf0[i], aQ0[j], z);                                        \
        z = MFMA(kf1[i], aQ1[j], z);                                        \
        S[i][j] = z;                                                        \
      }                                                                     \
    }                                                                       \
    __builtin_amdgcn_s_setprio(0);                                          \
    frag8 vf0[4], vf1[4];                                                   \
    _Pragma("unroll") for (int i = 0; i < 4; ++i) {                         \
      vf0[i] = *(const frag8*)(ldsbase + (CUR) + vAo + i * 1024);           \
      vf1[i] = *(const frag8*)(ldsbase + (CUR) + vBo + i * 1024);           \
    }                                                                       \
    _Pragma("unroll") for (int j = 0; j < 4; ++j) {                         \
      u32 pw[8];                                                            \
      _Pragma("unroll") for (int i = 0; i < 4; ++i) {                       \
        float p0 = __builtin_amdgcn_exp2f(S[i][j][0]);                      \
        float p1 = __builtin_amdgcn_exp2f(S[i][j][1]);                      \
        float p2 = __builtin_amdgcn_exp2f(S[i][j][2]);                      \
        float p3 = __builtin_amdgcn_exp2f(S[i][j][3]);                      \
        u32 a0 = __float_as_uint(p0) + 0x8000u;                             \
        u32 a1 = __float_as_uint(p1) + 0x8000u;                             \
        u32 a2 = __float_as_uint(p2) + 0x8000u;                             \
        u32 a3 = __float_as_uint(p3) + 0x8000u;                             \
        pw[i * 2] = __builtin_amdgcn_perm(a1, a0, 0x07060302u);             \
        pw[i * 2 + 1] = __builtin_amdgcn_perm(a3, a2, 0x07060302u);         \
      }                                                                     \
      u32x4 va = {pw[0], pw[1], pw[2], pw[3]};                              \
      u32x4 vb = {pw[4], pw[5], pw[6], pw[7]};                              \
      frag8 pf0 = __builtin_bit_cast(frag8, va);                            \
      frag8 pf1 = __builtin_bit_cast(frag8, vb);                            \
      __builtin_amdgcn_s_setprio(1);                                        \
      _Pragma("unroll") for (int i = 0; i < 4; ++i) {                       \
        o[i][j] = MFMA(vf0[i], pf0, o[i][j]);                               \
        o[i][j] = MFMA(vf1[i], pf1, o[i][j]);                               \
      }                                                                     \
      lacc[j] = MFMA(ones, pf0, lacc[j]);                                   \
      lacc[j] = MFMA(ones, pf1, lacc[j]);                                   \
      __builtin_amdgcn_s_setprio(0);                                        \
    }                                                                       \
    __syncthreads(); /* staging drained; buf CUR^1 ready */                 \
  }

__global__ __launch_bounds__(256, 2) void attn_flash_kernel(
    const u16* __restrict__ Qt, const u16* __restrict__ Kt,
    const u16* __restrict__ Vn, float* __restrict__ out) {
  __shared__ __align__(16) unsigned char smem[65536];
  u16* ldsbase = (u16*)smem;

  // XCD swizzle: blk&7 = XCD; 4 heads per XCD (K+V L2-resident per XCD)
  const int blk = blockIdx.x;
  const int ii = blk >> 3;
  const int b = ((blk & 7) << 2) + (ii >> 4);  // head 0..31
  const int qt = ii & 15;                      // q-tile (128 t each)

  const int tid = threadIdx.x;
  const int w = tid >> 6;
  const int tg = w & 1;   // t-group: t in [64*tg, 64*tg+64) of the q-tile
  const int sh = w >> 1;  // s-half: tiles [16*sh, 16*sh+16)
  const int lane = tid & 63;
  const int s16 = lane & 15, q = lane >> 4;
  const int x = s16 & 7;

  const u16* Qg = Qt + ((size_t)b * 2048 + qt * 128) * 64;
  const u16* Kg = Kt + (size_t)b * 2048 * 64;
  const u16* Vg = Vn + (size_t)b * 64 * 2048;

  // staging lane offsets (u16 units)
  const int srow = tid >> 3;
  const int sgl = (tid & 7) ^ (srow & 7);
  const int koff0 = srow * 64 + sgl * 8;    // pitch-64 tiles (Q,K)
  const int voff0 = srow * 2048 + sgl * 8;  // pitch-2048 (V)

  // fragment read offsets within a buffer (XOR-swizzled)
  const int kAo = sh * 4096 + s16 * 64 + ((q ^ x) * 8);
  const int kBo = sh * 4096 + s16 * 64 + (((q + 4) ^ x) * 8);
  const int vAo = 8192 + sh * 4096 + s16 * 64 + ((q ^ x) * 8);
  const int vBo = 8192 + sh * 4096 + s16 * 64 + (((q + 4) ^ x) * 8);
  const int off0 = (q ^ x) * 8;
  const int off1 = ((q + 4) ^ x) * 8;

  // prologue: stage Q (128x64 -> buf1 area) + K/V tiles {0,16} -> buf0
  STAGE(16384, Qg + koff0);
  STAGE(16384 + 2048, Qg + koff0 + 2048);
  STAGE(16384 + 4096, Qg + koff0 + 4096);
  STAGE(16384 + 6144, Qg + koff0 + 6144);
  STG_STEP(0, 0)
  __syncthreads();

  // loop-invariant Q fragments (both s-half waves read the shared Q rows)
  const u16* pqb = ldsbase + 16384 + tg * 4096 + s16 * 64;
  frag8 aQ0[4], aQ1[4];
#pragma unroll
  for (int j = 0; j < 4; ++j) {
    aQ0[j] = *(const frag8*)(pqb + j * 1024 + off0);
    aQ1[j] = *(const frag8*)(pqb + j * 1024 + off1);
  }
  __syncthreads();  // Q consumed by all before step 0 stages tile 1 over it

  // ones A-fragment (bf16 1.0) for the row-sum MFMA
  frag8 ones;
#pragma unroll
  for (int z = 0; z < 8; ++z) ones[z] = (short)0x3F80;

  f32x4 o[4][4];
#pragma unroll
  for (int i = 0; i < 4; ++i)
#pragma unroll
    for (int j = 0; j < 4; ++j) o[i][j] = (f32x4){0.f, 0.f, 0.f, 0.f};
  f32x4 lacc[4];
#pragma unroll
  for (int j = 0; j < 4; ++j) lacc[j] = (f32x4){0.f, 0.f, 0.f, 0.f};

  for (int n = 0; n < 14; n += 2) {
    BODY(0, STG_STEP(n + 1, 16384))
    BODY(16384, STG_STEP(n + 2, 0))
  }
  BODY(0, STG_STEP(15, 16384))
  BODY(16384, )  // tile 15/31, nothing left to stage

  // per-wave denominators: ones-MFMA summed all s of this wave's range for
  // t = 16j + s16 (every acc row identical) — no cross-lane reduction needed
  float lp[4];
#pragma unroll
  for (int j = 0; j < 4; ++j) lp[j] = lacc[j][0];

  // combine s-halves through LDS (all K/V buffers dead after final barrier)
  // O rows strided 68 floats (272 B) -> 4-bank rotation per lane
  if (sh == 1) {
    float* ow = (float*)ldsbase + tg * 4352 + lane * 68;
#pragma unroll
    for (int i = 0; i < 4; ++i)
#pragma unroll
      for (int j = 0; j < 4; ++j) *(f32x4*)(ow + (i * 4 + j) * 4) = o[i][j];
    float* lw = (float*)ldsbase + 8704 + tg * 256 + lane * 4;
#pragma unroll
    for (int j = 0; j < 4; ++j) lw[j] = lp[j];
  }
  __syncthreads();
  if (sh == 0) {
    const float* ow = (const float*)ldsbase + tg * 4352 + lane * 68;
    const float* lw = (const float*)ldsbase + 8704 + tg * 256 + lane * 4;
    float rl[4];
#pragma unroll
    for (int j = 0; j < 4; ++j) rl[j] = 1.0f / (lp[j] + lw[j]);
    // lane stores O^T[c = i*16+q*4+r][t = qt*128 + tg*64 + 16j + s16]
    float* ob =
        out + (size_t)(b * 64 + q * 4) * 2048 + qt * 128 + tg * 64 + s16;
#pragma unroll
    for (int i = 0; i < 4; ++i)
#pragma unroll
      for (int j = 0; j < 4; ++j) {
        f32x4 oo = *(const f32x4*)(ow + (i * 4 + j) * 4);
#pragma unroll
        for (int r = 0; r < 4; ++r)
          ob[(size_t)(i * 16 + r) * 2048 + j * 16] =
              (o[i][j][r] + oo[r]) * rl[j];
      }
  }
}

extern "C" void kernel_launch(void* const* d_in, const int* in_sizes, int n_in,
                              void* d_out, int out_size, void* d_ws,
                              size_t ws_size, hipStream_t stream) {
  const float* qkv = (const float*)d_in[0];
  float* out = (float*)d_out;
  u16* Qt = (u16*)d_ws;
  u16* Kt = Qt + (size_t)32 * 2048 * 64;
  u16* Vn = Kt + (size_t)32 * 2048 * 64;

  qkv_prepass_kernel<<<3072, 256, 0, stream>>>(qkv, Qt, Kt, Vn);
  attn_flash_kernel<<<512, 256, 0, stream>>>(Qt, Kt, Vn, out);
}

// Round 6
// 122.631 us; speedup vs baseline: 1.0754x; 1.0099x over previous
//
#include <hip/hip_runtime.h>

typedef unsigned short u16;
typedef unsigned int u32;
using frag8 = __attribute__((ext_vector_type(8))) short;  // 8 bf16 (4 VGPRs)
using f32x4 = __attribute__((ext_vector_type(4))) float;
using u32x4 = __attribute__((ext_vector_type(4))) u32;

#define MFMA(a, b, c) __builtin_amdgcn_mfma_f32_16x16x32_bf16(a, b, c, 0, 0, 0)

// fp32 -> bf16, round-to-nearest-even (finite inputs only)
__device__ __forceinline__ u16 f2bf(float f) {
  u32 x = __float_as_uint(f);
  x += 0x7fffu + ((x >> 16) & 1u);
  return (u16)(x >> 16);
}

// ---------------------------------------------------------------------------
// Pre-pass: qkv (4,1536,2048) fp32 ->
//   Qt[b][t][c] bf16 (scaled), Kt[b][s][c] bf16 (scaled),
//   Vn[b][c][s'] bf16 with s sigma-PERMUTED within each 64-s tile:
//     stored position p (h=p>>5, w=(p>>3)&3, e=p&7) holds original
//     s = 32h + 16*(e>>2) + 4w + (e&3).
// NOTE: the permutation maps each 32-s half onto itself (p<32 -> s<32), so
// 32-s tiles (R6) remain valid. Makes QK^T's D-fragment directly usable as
// PV's B-fragment (k-permutation cancels between P and V) -> P stays in regs.
// ---------------------------------------------------------------------------
__global__ __launch_bounds__(256) void qkv_prepass_kernel(
    const float* __restrict__ qkv, u16* __restrict__ Qt, u16* __restrict__ Kt,
    u16* __restrict__ Vn) {
  __shared__ float tile[64 * 65];
  const int id = blockIdx.x;
  const int tid = threadIdx.x;

  if (id < 2048) {
    const bool isK = id >= 1024;
    const int lid = isK ? (id - 1024) : id;
    const int b = lid >> 5;
    const int t0 = (lid & 31) * 64;
    const int bs = b >> 3, h = b & 7;
    const float* src =
        qkv + ((size_t)(bs * 1536 + h * 192 + (isK ? 64 : 0))) * 2048 + t0;
    u16* dst = (isK ? Kt : Qt) + ((size_t)b * 2048 + t0) * 64;
    const float scale = 0.42466090014400953f;  // 64^-0.25 * sqrt(log2 e)

    const int t4 = (tid & 15) * 4;
    const int c = tid >> 4;
#pragma unroll
    for (int i = 0; i < 4; ++i) {
      int cc = c + 16 * i;
      float4 f = *reinterpret_cast<const float4*>(src + (size_t)cc * 2048 + t4);
      tile[cc * 65 + t4 + 0] = f.x * scale;
      tile[cc * 65 + t4 + 1] = f.y * scale;
      tile[cc * 65 + t4 + 2] = f.z * scale;
      tile[cc * 65 + t4 + 3] = f.w * scale;
    }
    __syncthreads();
    const int c0 = (tid & 7) * 8;
#pragma unroll
    for (int p = 0; p < 2; ++p) {
      int tr = (tid >> 3) + 32 * p;
      u32 pk[4];
#pragma unroll
      for (int uu = 0; uu < 4; ++uu) {
        u16 lo = f2bf(tile[(c0 + 2 * uu) * 65 + tr]);
        u16 hi = f2bf(tile[(c0 + 2 * uu + 1) * 65 + tr]);
        pk[uu] = (u32)lo | ((u32)hi << 16);
      }
      *reinterpret_cast<uint4*>(dst + (size_t)tr * 64 + c0) =
          make_uint4(pk[0], pk[1], pk[2], pk[3]);
    }
  } else {
    const size_t base = (size_t)(id - 2048) * 4096;
#pragma unroll
    for (int it = 0; it < 2; ++it) {
      size_t vi = base + (size_t)it * 2048 + (size_t)tid * 8;
      int b = (int)(vi >> 17);
      int r = (int)(vi & 131071);
      int bs = b >> 3, h = b & 7;
      int col = r & 2047;      // stored position within the c-row
      int rowoff = r - col;    // c * 2048
      int m = (col >> 3) & 7;  // 8-run index within the 64-s tile
      // source column of stored e=0..3 run: tilebase + 32h + 4w
      int c0 = (col & ~63) | ((m >> 2) << 5) | ((m & 3) << 2);
      const float* sp =
          qkv + ((size_t)(bs * 1536 + h * 192 + 128)) * 2048 + rowoff;
      float4 f0 = *reinterpret_cast<const float4*>(sp + c0);       // e=0..3
      float4 f1 = *reinterpret_cast<const float4*>(sp + c0 + 16);  // e=4..7
      uint4 pk;
      pk.x = (u32)f2bf(f0.x) | ((u32)f2bf(f0.y) << 16);
      pk.y = (u32)f2bf(f0.z) | ((u32)f2bf(f0.w) << 16);
      pk.z = (u32)f2bf(f1.x) | ((u32)f2bf(f1.y) << 16);
      pk.w = (u32)f2bf(f1.z) | ((u32)f2bf(f1.w) << 16);
      *reinterpret_cast<uint4*>(Vn + vi) = pk;
    }
  }
}

// ---------------------------------------------------------------------------
// Flash attention R6: 8-wave blocks for 16 waves/CU (was 8).
// block = 512 threads = 8 waves = 4 t-groups (32 t) x 2 s-halves (1024 s).
// 32-s K/V tiles, 32 steps, double-buffered; P in registers (R3 trick).
// R5 showed both pipes <40% at 2 waves/SIMD -> latency-bound; this doubles
// waves/SIMD to 4 so independent wave streams cover softmax/barrier phases.
// LDS (u16 units, 36 KiB total):
//   buf0 [0,8192):     K sh0 [0,2K) K sh1 [2K,4K) V sh0 [4K,6K) V sh1 [6K,8K)
//   buf1 [8192,16384): same; Q (prologue only) occupies buf1 exactly
//   epilogue O/l exchange: [0, 9216) floats = 36 KiB
// 2 blocks/CU x 36 KiB = 72 KiB <= 160; __launch_bounds__(512,4) forces
// VGPR <= 128 for 4 waves/SIMD.
// ---------------------------------------------------------------------------
#define STAGE(dstOff, srcPtr)                                                  \
  __builtin_amdgcn_global_load_lds(                                            \
      (const __attribute__((address_space(1))) void*)(srcPtr),                 \
      (__attribute__((address_space(3))) void*)(ldsbase + (dstOff) + tid * 8), \
      16, 0, 0)

// stage K tiles (both s-halves, one 8KiB call) + V likewise into buf B
#define STG_STEP(N, B)                  \
  STAGE((B), kS + (size_t)(N) * 2048); \
  STAGE((B) + 4096, vS + (N) * 32);

// step: read K frags from buf CUR -> stage next tile into buf CUR^1 (async,
// different buffer) -> S MFMA -> vf reads -> per-j {exp/pack -> PV + l-MFMA}
// -> barrier (staging drained; all waves done reading CUR)
#define BODY(CUR, STG)                                                      \
  {                                                                         \
    frag8 kf0[2], kf1[2];                                                   \
    _Pragma("unroll") for (int i = 0; i < 2; ++i) {                         \
      kf0[i] = *(const frag8*)(ldsbase + (CUR) + kAo + i * 1024);           \
      kf1[i] = *(const frag8*)(ldsbase + (CUR) + kBo + i * 1024);           \
    }                                                                       \
    STG                                                                     \
    f32x4 S[2][2];                                                          \
    __builtin_amdgcn_s_setprio(1);                                          \
    _Pragma("unroll") for (int j = 0; j < 2; ++j) {                         \
      _Pragma("unroll") for (int i = 0; i < 2; ++i) {                       \
        f32x4 z = {0.f, 0.f, 0.f, 0.f};                                     \
        z = MFMA(kf0[i], aQ0[j], z);                                        \
        z = MFMA(kf1[i], aQ1[j], z);                                        \
        S[i][j] = z;                                                        \
      }                                                                     \
    }                                                                       \
    __builtin_amdgcn_s_setprio(0);                                          \
    frag8 vf[4];                                                            \
    _Pragma("unroll") for (int i = 0; i < 4; ++i)                           \
      vf[i] = *(const frag8*)(ldsbase + (CUR) + vAo + i * 512);             \
    _Pragma("unroll") for (int j = 0; j < 2; ++j) {                         \
      u32 pw[4];                                                            \
      _Pragma("unroll") for (int i = 0; i < 2; ++i) {                       \
        float p0 = __builtin_amdgcn_exp2f(S[i][j][0]);                      \
        float p1 = __builtin_amdgcn_exp2f(S[i][j][1]);                      \
        float p2 = __builtin_amdgcn_exp2f(S[i][j][2]);                      \
        float p3 = __builtin_amdgcn_exp2f(S[i][j][3]);                      \
        u32 a0 = __float_as_uint(p0) + 0x8000u;                             \
        u32 a1 = __float_as_uint(p1) + 0x8000u;                             \
        u32 a2 = __float_as_uint(p2) + 0x8000u;                             \
        u32 a3 = __float_as_uint(p3) + 0x8000u;                             \
        pw[i * 2] = __builtin_amdgcn_perm(a1, a0, 0x07060302u);             \
        pw[i * 2 + 1] = __builtin_amdgcn_perm(a3, a2, 0x07060302u);         \
      }                                                                     \
      u32x4 va = {pw[0], pw[1], pw[2], pw[3]};                              \
      frag8 pf = __builtin_bit_cast(frag8, va);                             \
      __builtin_amdgcn_s_setprio(1);                                        \
      _Pragma("unroll") for (int i = 0; i < 4; ++i)                         \
          o[i][j] = MFMA(vf[i], pf, o[i][j]);                               \
      lacc[j] = MFMA(ones, pf, lacc[j]);                                    \
      __builtin_amdgcn_s_setprio(0);                                        \
    }                                                                       \
    __syncthreads(); /* staging drained; buf CUR^1 ready */                 \
  }

__global__ __launch_bounds__(512, 4) void attn_flash_kernel(
    const u16* __restrict__ Qt, const u16* __restrict__ Kt,
    const u16* __restrict__ Vn, float* __restrict__ out) {
  __shared__ __align__(16) unsigned char smem[36864];
  u16* ldsbase = (u16*)smem;

  // XCD swizzle: blk&7 = XCD; 4 heads per XCD (K+V L2-resident per XCD)
  const int blk = blockIdx.x;
  const int ii = blk >> 3;
  const int b = ((blk & 7) << 2) + (ii >> 4);  // head 0..31
  const int qt = ii & 15;                      // q-tile (128 t each)

  const int tid = threadIdx.x;  // 0..511
  const int w = tid >> 6;
  const int tg = w & 3;   // t-group: t in [32*tg, 32*tg+32) of the q-tile
  const int sh = w >> 2;  // s-half: s in [1024*sh, 1024*sh+1024)
  const int lane = tid & 63;
  const int s16 = lane & 15, q = lane >> 4;
  const int x = s16 & 7;
  const int x2 = (s16 >> 1) & 3;

  const u16* Qg = Qt + ((size_t)b * 2048 + qt * 128) * 64;
  const u16* Kg = Kt + (size_t)b * 2048 * 64;
  const u16* Vg = Vn + (size_t)b * 64 * 2048;

  // staging source pointers (pre-swizzled; 512 threads = 2 x 256-lane groups)
  const int inner = tid & 255;
  const int gsel = tid >> 8;  // selects s-half within a staging call
  const int srow = inner >> 3;
  const int sgl = (inner & 7) ^ (srow & 7);
  const u16* kS = Kg + gsel * 65536 + srow * 64 + sgl * 8;  // K rows, pitch 64
  const u16* vS = Vg + gsel * 1024 + (inner >> 2) * 2048 +
                  ((((inner & 3) ^ ((inner >> 3) & 3))) * 8);  // V pitch 2048
  const int qrow = tid >> 3;  // Q staging rows over 512 threads
  const u16* qS = Qg + qrow * 64 + (((tid & 7) ^ (qrow & 7)) * 8);

  // fragment read offsets within a buffer (XOR-swizzled)
  const int kAo = sh * 2048 + s16 * 64 + ((q ^ x) * 8);
  const int kBo = sh * 2048 + s16 * 64 + (((q + 4) ^ x) * 8);
  const int vAo = 4096 + sh * 2048 + s16 * 32 + ((q ^ x2) * 8);
  const int off0 = (q ^ x) * 8;
  const int off1 = ((q + 4) ^ x) * 8;

  // prologue: stage Q (128x64 -> buf1, 2 calls) + K/V tile 0 -> buf0
  STAGE(8192, qS);
  STAGE(8192 + 4096, qS + 4096);
  STG_STEP(0, 0)
  __syncthreads();

  // loop-invariant Q fragments (each wave reads its own 32 t rows)
  const u16* pqb = ldsbase + 8192 + tg * 2048 + s16 * 64;
  frag8 aQ0[2], aQ1[2];
#pragma unroll
  for (int j = 0; j < 2; ++j) {
    aQ0[j] = *(const frag8*)(pqb + j * 1024 + off0);
    aQ1[j] = *(const frag8*)(pqb + j * 1024 + off1);
  }
  __syncthreads();  // Q consumed by all before step 0 stages tile 1 over it

  // ones A-fragment (bf16 1.0) for the row-sum MFMA
  frag8 ones;
#pragma unroll
  for (int z = 0; z < 8; ++z) ones[z] = (short)0x3F80;

  f32x4 o[4][2];
#pragma unroll
  for (int i = 0; i < 4; ++i)
#pragma unroll
    for (int j = 0; j < 2; ++j) o[i][j] = (f32x4){0.f, 0.f, 0.f, 0.f};
  f32x4 lacc[2];
#pragma unroll
  for (int j = 0; j < 2; ++j) lacc[j] = (f32x4){0.f, 0.f, 0.f, 0.f};

  for (int n = 0; n < 30; n += 2) {
    BODY(0, STG_STEP(n + 1, 8192))
    BODY(8192, STG_STEP(n + 2, 0))
  }
  BODY(0, STG_STEP(31, 8192))
  BODY(8192, )  // tile 31, nothing left to stage

  // per-wave denominators from the ones-MFMA (all acc rows identical)
  float lp[2];
#pragma unroll
  for (int j = 0; j < 2; ++j) lp[j] = lacc[j][0];

  // combine s-halves through LDS (bufs dead after final barrier)
  // per lane: 8 f32x4 (o) + 2 floats (lp), stride 36 floats (144 B)
  float* fb = (float*)ldsbase;
  if (sh == 1) {
    float* ow = fb + tg * 2304 + lane * 36;
#pragma unroll
    for (int i = 0; i < 4; ++i)
#pragma unroll
      for (int j = 0; j < 2; ++j) *(f32x4*)(ow + (i * 2 + j) * 4) = o[i][j];
    ow[32] = lp[0];
    ow[33] = lp[1];
  }
  __syncthreads();
  if (sh == 0) {
    const float* ow = fb + tg * 2304 + lane * 36;
    float rl[2];
#pragma unroll
    for (int j = 0; j < 2; ++j) rl[j] = 1.0f / (lp[j] + ow[32 + j]);
    // lane stores O^T[c = i*16+q*4+r][t = qt*128 + tg*32 + 16j + s16]
    float* ob =
        out + (size_t)(b * 64 + q * 4) * 2048 + qt * 128 + tg * 32 + s16;
#pragma unroll
    for (int i = 0; i < 4; ++i)
#pragma unroll
      for (int j = 0; j < 2; ++j) {
        f32x4 oo = *(const f32x4*)(ow + (i * 2 + j) * 4);
#pragma unroll
        for (int r = 0; r < 4; ++r)
          ob[(size_t)(i * 16 + r) * 2048 + j * 16] =
              (o[i][j][r] + oo[r]) * rl[j];
      }
  }
}

extern "C" void kernel_launch(void* const* d_in, const int* in_sizes, int n_in,
                              void* d_out, int out_size, void* d_ws,
                              size_t ws_size, hipStream_t stream) {
  const float* qkv = (const float*)d_in[0];
  float* out = (float*)d_out;
  u16* Qt = (u16*)d_ws;
  u16* Kt = Qt + (size_t)32 * 2048 * 64;
  u16* Vn = Kt + (size_t)32 * 2048 * 64;

  qkv_prepass_kernel<<<3072, 256, 0, stream>>>(qkv, Qt, Kt, Vn);
  attn_flash_kernel<<<512, 512, 0, stream>>>(Qt, Kt, Vn, out);
}